// Round 4
// baseline (265.161 us; speedup 1.0000x reference)
//
#include <hip/hip_runtime.h>
#include <math.h>

// Shapes fixed by the problem: B=8, h=8, H=W=64, d=32, WS=8x8
// BH = 64 maps, L = 4096 pixels/map, L_ = 64 clusters/map.
// d_out layout: c_q [64*64*32] | c_v [64*64*32] | rpb [64*4096*64]
// ws layout (floats): cq0[131072] | ch[4096] | cw[4096] | partials[512*4288]

#define NMAPS   64
#define LPIX    4096
#define NCLUS   64
#define DIM     32
#define CHUNKS  8           // chunks per map in assign kernel
#define PSTRIDE 4288        // per-block partial: 2048 k + 2048 v + 64 s + 64 ch + 64 cw

__global__ __launch_bounds__(256) void k_initcenter(const float* __restrict__ xk,
                                                    float* __restrict__ cq0) {
    int wid  = threadIdx.x >> 6;
    int lane = threadIdx.x & 63;
    int c    = blockIdx.x * 4 + wid;        // center id 0..4095
    int bh   = c >> 6, m = c & 63;
    int wh   = m >> 3, wc = m & 7;
    int d    = lane & 31, half = lane >> 5;
    const float* base = xk + (size_t)bh * LPIX * DIM;
    float s = 0.f;
#pragma unroll
    for (int k = 0; k < 32; ++k) {
        int pix = k * 2 + half;             // 0..63 within window
        int r = pix >> 3, cc = pix & 7;
        int row = wh * 8 + r, col = wc * 8 + cc;
        s += base[((row << 6) + col) * DIM + d];
    }
    s += __shfl_xor(s, 32);                 // full 64-pixel sum per dim
    float ss = s * s;
#pragma unroll
    for (int o = 16; o >= 1; o >>= 1) ss += __shfl_xor(ss, o);   // sum over 32 dims
    float mean = s * (1.0f / 64.0f);
    float norm = sqrtf(ss) * (1.0f / 64.0f);
    float inv  = 1.0f / fmaxf(norm, 1e-12f);
    if (half == 0) cq0[(size_t)c * DIM + d] = mean * inv;
}

__global__ __launch_bounds__(256) void k_assign(const float* __restrict__ xk,
                                                const float* __restrict__ xv,
                                                const float* __restrict__ scale,
                                                const float* __restrict__ cq0,
                                                float* __restrict__ partial) {
    __shared__ float cs[NCLUS * DIM];       // 8 KB centers
    __shared__ float aq[NCLUS * 33];        // padded accumulators (bank-spread)
    __shared__ float av[NCLUS * 33];
    __shared__ float as_[NCLUS], ach[NCLUS], acw[NCLUS];

    int t     = threadIdx.x;
    int bh    = blockIdx.x >> 3;
    int chunk = blockIdx.x & (CHUNKS - 1);

#pragma unroll
    for (int i = 0; i < 8; ++i) cs[t + i * 256] = cq0[(size_t)bh * 2048 + t + i * 256];
    for (int i = t; i < NCLUS * 33; i += 256) { aq[i] = 0.f; av[i] = 0.f; }
    if (t < NCLUS) { as_[t] = 0.f; ach[t] = 0.f; acw[t] = 0.f; }
    __syncthreads();

    float qs = 0.17677669529663687f * scale[0];
    const float* xkb = xk + (size_t)bh * LPIX * DIM;
    const float* xvb = xv + (size_t)bh * LPIX * DIM;

    for (int pp = 0; pp < 2; ++pp) {
        int l = chunk * 512 + pp * 256 + t;      // pixel in map
        float fi = (float)(l >> 6);
        float fj = (float)(l & 63);

        float xr[DIM];
        const float4* xp = (const float4*)(xkb + (size_t)l * DIM);
#pragma unroll
        for (int k = 0; k < 8; ++k) {
            float4 v = xp[k];
            xr[k*4] = v.x; xr[k*4+1] = v.y; xr[k*4+2] = v.z; xr[k*4+3] = v.w;
        }

        float mx = -INFINITY;
        unsigned long long msk = 0ull;
        for (int m = 0; m < NCLUS; ++m) {
            const float4* cm4 = (const float4*)&cs[m * DIM];
            float dot = 0.f;
#pragma unroll
            for (int k = 0; k < 8; ++k) {
                float4 c4 = cm4[k];
                dot = fmaf(xr[k*4],   c4.x, dot);
                dot = fmaf(xr[k*4+1], c4.y, dot);
                dot = fmaf(xr[k*4+2], c4.z, dot);
                dot = fmaf(xr[k*4+3], c4.w, dot);
            }
            // initial RPE: window centers are analytic (wh*8+3.5, ww*8+3.5)
            float dh = fi - (float)((m >> 3) * 8) - 3.5f;
            float dw = fj - (float)((m & 7) * 8) - 3.5f;
            float rp = expf(-sqrtf(fmaf(dh, dh, dw * dw)));
            float val = fmaf(dot, qs, rp);
            if (val > mx)       { mx = val; msk = 1ull << m; }
            else if (val == mx) { msk |= 1ull << m; }
        }
        float w = 1.0f / (float)__popcll(msk);

        float vr[DIM];
        const float4* vp = (const float4*)(xvb + (size_t)l * DIM);
#pragma unroll
        for (int k = 0; k < 8; ++k) {
            float4 v = vp[k];
            vr[k*4] = v.x; vr[k*4+1] = v.y; vr[k*4+2] = v.z; vr[k*4+3] = v.w;
        }

        while (msk) {
            int m = __builtin_ctzll(msk);
            msk &= msk - 1;
            float* aqm = &aq[m * 33];
            float* avm = &av[m * 33];
#pragma unroll
            for (int d = 0; d < DIM; ++d) {
                atomicAdd(&aqm[d], w * xr[d]);
                atomicAdd(&avm[d], w * vr[d]);
            }
            atomicAdd(&as_[m], w);
            atomicAdd(&ach[m], w * fi);
            atomicAdd(&acw[m], w * fj);
        }
    }
    __syncthreads();

    float* pw = partial + (size_t)blockIdx.x * PSTRIDE;
    for (int i = t; i < 2048; i += 256) {
        pw[i]        = aq[(i >> 5) * 33 + (i & 31)];
        pw[2048 + i] = av[(i >> 5) * 33 + (i & 31)];
    }
    if (t < NCLUS) {
        pw[4096 + t] = as_[t];
        pw[4160 + t] = ach[t];
        pw[4224 + t] = acw[t];
    }
}

__global__ __launch_bounds__(256) void k_reduce(const float* __restrict__ partial,
                                                float* __restrict__ out,
                                                float* __restrict__ cen) {
    __shared__ float sk[2048], sv[2048];
    __shared__ float ss_[NCLUS], sch[NCLUS], scw[NCLUS];
    __shared__ float invq[NCLUS], invv[NCLUS];
    int bh = blockIdx.x, t = threadIdx.x;
    const float* pw = partial + (size_t)bh * CHUNKS * PSTRIDE;

    for (int i = t; i < 2048; i += 256) {
        float a = 0.f, b = 0.f;
#pragma unroll
        for (int p = 0; p < CHUNKS; ++p) {
            a += pw[(size_t)p * PSTRIDE + i];
            b += pw[(size_t)p * PSTRIDE + 2048 + i];
        }
        sk[i] = a; sv[i] = b;
    }
    if (t < NCLUS) {
        float a = 0.f, b = 0.f, c = 0.f;
#pragma unroll
        for (int p = 0; p < CHUNKS; ++p) {
            a += pw[(size_t)p * PSTRIDE + 4096 + t];
            b += pw[(size_t)p * PSTRIDE + 4160 + t];
            c += pw[(size_t)p * PSTRIDE + 4224 + t];
        }
        ss_[t] = a; sch[t] = b; scw[t] = c;
    }
    __syncthreads();
    if (t < NCLUS) {
        float s2 = 0.f;
#pragma unroll
        for (int d = 0; d < DIM; ++d) { float v = sk[t * DIM + d]; s2 = fmaf(v, v, s2); }
        invq[t] = 1.0f / fmaxf(sqrtf(s2), 1e-12f);
        float s  = ss_[t];
        float sp = (s == 0.f) ? 1.f : s;
        invv[t] = 1.0f / sp;
        cen[bh * NCLUS + t]        = sch[t] / sp;   // ch centroid
        cen[4096 + bh * NCLUS + t] = scw[t] / sp;   // cw centroid
    }
    __syncthreads();
    float* cq = out;
    float* cv = out + 131072;
    for (int i = t; i < 2048; i += 256) {
        int m = i >> 5;
        cq[(size_t)bh * 2048 + i] = sk[i] * invq[m];
        cv[(size_t)bh * 2048 + i] = sv[i] * invv[m];
    }
}

__global__ __launch_bounds__(256) void k_rpb(const float* __restrict__ cen,
                                             float* __restrict__ out) {
    size_t g = (size_t)blockIdx.x * 256 + threadIdx.x;   // 0 .. 16777215
    int m      = (int)(g & 63);
    size_t lbh = g >> 6;
    int l  = (int)(lbh & 4095);
    int bh = (int)(lbh >> 12);
    float fi = (float)(l >> 6);
    float fj = (float)(l & 63);
    float ch = cen[bh * NCLUS + m];
    float cw = cen[4096 + bh * NCLUS + m];
    float dh = fi - ch, dw = fj - cw;
    out[262144 + g] = expf(-sqrtf(fmaf(dh, dh, dw * dw)));
}

extern "C" void kernel_launch(void* const* d_in, const int* in_sizes, int n_in,
                              void* d_out, int out_size, void* d_ws, size_t ws_size,
                              hipStream_t stream) {
    const float* xk    = (const float*)d_in[0];
    const float* xv    = (const float*)d_in[1];
    const float* scale = (const float*)d_in[2];
    float* out = (float*)d_out;
    float* ws  = (float*)d_ws;

    float* cq0     = ws;                  // 131072 floats
    float* cen     = ws + 131072;         // 8192 floats (ch | cw)
    float* partial = ws + 139264;         // 512 * 4288 floats  (~8.8 MB)

    k_initcenter<<<1024, 256, 0, stream>>>(xk, cq0);
    k_assign<<<NMAPS * CHUNKS, 256, 0, stream>>>(xk, xv, scale, cq0, partial);
    k_reduce<<<NMAPS, 256, 0, stream>>>(partial, out, cen);
    k_rpb<<<65536, 256, 0, stream>>>(cen, out);
}

// Round 7
// 250.729 us; speedup vs baseline: 1.0576x; 1.0576x over previous
//
#include <hip/hip_runtime.h>
#include <math.h>

// Shapes fixed by the problem: B=8, h=8, H=W=64, d=32, WS=8x8
// BH = 64 maps, L = 4096 pixels/map, L_ = 64 clusters/map.
// d_out layout: c_q [64*64*32] | c_v [64*64*32] | rpb [64*4096*64]
// ws (floats): cq0[131072] | cen[8192] | partial[512*4288] | rp0[262144]

#define NMAPS   64
#define LPIX    4096
#define NCLUS   64
#define DIM     32
#define CHUNKS  8           // chunks per map in assign kernel (512 pixels each)
#define PSTRIDE 4288        // per-block partial: 2048 k + 2048 v + 64 s + 64 ch + 64 cw

__global__ __launch_bounds__(256) void k_initcenter(const float* __restrict__ xk,
                                                    float* __restrict__ cq0) {
    int wid  = threadIdx.x >> 6;
    int lane = threadIdx.x & 63;
    int c    = blockIdx.x * 4 + wid;        // center id 0..4095
    int bh   = c >> 6, m = c & 63;
    int wh   = m >> 3, wc = m & 7;
    int d    = lane & 31, half = lane >> 5;
    const float* base = xk + (size_t)bh * LPIX * DIM;
    float s = 0.f;
#pragma unroll
    for (int k = 0; k < 32; ++k) {
        int pix = k * 2 + half;             // 0..63 within window
        int r = pix >> 3, cc = pix & 7;
        int row = wh * 8 + r, col = wc * 8 + cc;
        s += base[((row << 6) + col) * DIM + d];
    }
    s += __shfl_xor(s, 32);                 // full 64-pixel sum per dim
    float ss = s * s;
#pragma unroll
    for (int o = 16; o >= 1; o >>= 1) ss += __shfl_xor(ss, o);   // sum over 32 dims
    float mean = s * (1.0f / 64.0f);
    float norm = sqrtf(ss) * (1.0f / 64.0f);
    float inv  = 1.0f / fmaxf(norm, 1e-12f);
    if (half == 0) cq0[(size_t)c * DIM + d] = mean * inv;
}

// initial RPE table: map-independent, exp(-dist(pixel, analytic window center))
__global__ __launch_bounds__(256) void k_rpe0(float* __restrict__ rp0) {
    int g = blockIdx.x * 256 + threadIdx.x;   // 0..262143  (l*64+m)
    int m = g & 63, l = g >> 6;
    float fi = (float)(l >> 6);
    float fj = (float)(l & 63);
    float dh = fi - (float)((m >> 3) * 8) - 3.5f;
    float dw = fj - (float)((m & 7) * 8) - 3.5f;
    rp0[g] = expf(-sqrtf(fmaf(dh, dh, dw * dw)));
}

__global__ __launch_bounds__(512) void k_assign(const float* __restrict__ xk,
                                                const float* __restrict__ xv,
                                                const float* __restrict__ scale,
                                                const float* __restrict__ cq0,
                                                const float* __restrict__ rp0,
                                                float* __restrict__ partial) {
    __shared__ float aq[2][NCLUS * 33];     // 2 replicas (lane parity) vs atomic serialization
    __shared__ float av[2][NCLUS * 33];
    __shared__ float as_[2][NCLUS], ach[2][NCLUS], acw[2][NCLUS];

    int t     = threadIdx.x;
    int bh    = blockIdx.x >> 3;
    int chunk = blockIdx.x & (CHUNKS - 1);

    {
        float* aqf = &aq[0][0];
        float* avf = &av[0][0];
        for (int i = t; i < 2 * NCLUS * 33; i += 512) { aqf[i] = 0.f; avf[i] = 0.f; }
        if (t < 2 * NCLUS) { (&as_[0][0])[t] = 0.f; (&ach[0][0])[t] = 0.f; (&acw[0][0])[t] = 0.f; }
    }
    __syncthreads();

    float qs = 0.17677669529663687f * scale[0];
    const float* cqb = cq0 + (size_t)bh * 2048;      // wave-uniform reads -> scalar loads
    const float* xkb = xk + (size_t)bh * LPIX * DIM;
    const float* xvb = xv + (size_t)bh * LPIX * DIM;

    int l = chunk * 512 + t;                         // one pixel per thread
    float fi = (float)(l >> 6);
    float fj = (float)(l & 63);

    float xr[DIM];
    const float4* xp = (const float4*)(xkb + (size_t)l * DIM);
#pragma unroll
    for (int k = 0; k < 8; ++k) {
        float4 v = xp[k];
        xr[k*4] = v.x; xr[k*4+1] = v.y; xr[k*4+2] = v.z; xr[k*4+3] = v.w;
    }

    const float4* rpl = (const float4*)(rp0 + (size_t)l * 64);
    float mx = -INFINITY;
    unsigned long long msk = 0ull;
#pragma unroll
    for (int m4 = 0; m4 < 16; ++m4) {
        float4 r4 = rpl[m4];
        float rj[4] = {r4.x, r4.y, r4.z, r4.w};
#pragma unroll
        for (int j = 0; j < 4; ++j) {
            int m = m4 * 4 + j;
            const float* cm = cqb + m * DIM;
            float dot = 0.f;
#pragma unroll
            for (int k = 0; k < DIM; ++k) dot = fmaf(xr[k], cm[k], dot);
            float val = fmaf(dot, qs, rj[j]);
            if (val > mx)       { mx = val; msk = 1ull << m; }
            else if (val == mx) { msk |= 1ull << m; }
        }
    }
    float w = 1.0f / (float)__popcll(msk);

    float vr[DIM];
    const float4* vp = (const float4*)(xvb + (size_t)l * DIM);
#pragma unroll
    for (int k = 0; k < 8; ++k) {
        float4 v = vp[k];
        vr[k*4] = v.x; vr[k*4+1] = v.y; vr[k*4+2] = v.z; vr[k*4+3] = v.w;
    }

    int rep = t & 1;
    while (msk) {
        int m = __builtin_ctzll(msk);
        msk &= msk - 1;
        float* aqm = &aq[rep][m * 33];
        float* avm = &av[rep][m * 33];
#pragma unroll
        for (int d = 0; d < DIM; ++d) {
            atomicAdd(&aqm[d], w * xr[d]);
            atomicAdd(&avm[d], w * vr[d]);
        }
        atomicAdd(&as_[rep][m], w);
        atomicAdd(&ach[rep][m], w * fi);
        atomicAdd(&acw[rep][m], w * fj);
    }
    __syncthreads();

    float* pw = partial + (size_t)blockIdx.x * PSTRIDE;
    for (int i = t; i < 2048; i += 512) {
        int s = (i >> 5) * 33 + (i & 31);
        pw[i]        = aq[0][s] + aq[1][s];
        pw[2048 + i] = av[0][s] + av[1][s];
    }
    if (t < NCLUS) {
        pw[4096 + t] = as_[0][t] + as_[1][t];
        pw[4160 + t] = ach[0][t] + ach[1][t];
        pw[4224 + t] = acw[0][t] + acw[1][t];
    }
}

__global__ __launch_bounds__(256) void k_reduce(const float* __restrict__ partial,
                                                float* __restrict__ out,
                                                float* __restrict__ cen) {
    __shared__ float sk[2048], sv[2048];
    __shared__ float ss_[NCLUS], sch[NCLUS], scw[NCLUS];
    __shared__ float invq[NCLUS], invv[NCLUS];
    int bh = blockIdx.x, t = threadIdx.x;
    const float* pw = partial + (size_t)bh * CHUNKS * PSTRIDE;

    for (int i = t; i < 2048; i += 256) {
        float a = 0.f, b = 0.f;
#pragma unroll
        for (int p = 0; p < CHUNKS; ++p) {
            a += pw[(size_t)p * PSTRIDE + i];
            b += pw[(size_t)p * PSTRIDE + 2048 + i];
        }
        sk[i] = a; sv[i] = b;
    }
    if (t < NCLUS) {
        float a = 0.f, b = 0.f, c = 0.f;
#pragma unroll
        for (int p = 0; p < CHUNKS; ++p) {
            a += pw[(size_t)p * PSTRIDE + 4096 + t];
            b += pw[(size_t)p * PSTRIDE + 4160 + t];
            c += pw[(size_t)p * PSTRIDE + 4224 + t];
        }
        ss_[t] = a; sch[t] = b; scw[t] = c;
    }
    __syncthreads();
    if (t < NCLUS) {
        float s2 = 0.f;
#pragma unroll
        for (int d = 0; d < DIM; ++d) { float v = sk[t * DIM + d]; s2 = fmaf(v, v, s2); }
        invq[t] = 1.0f / fmaxf(sqrtf(s2), 1e-12f);
        float s  = ss_[t];
        float sp = (s == 0.f) ? 1.f : s;
        invv[t] = 1.0f / sp;
        cen[bh * NCLUS + t]        = sch[t] / sp;   // ch centroid
        cen[4096 + bh * NCLUS + t] = scw[t] / sp;   // cw centroid
    }
    __syncthreads();
    float* cq = out;
    float* cv = out + 131072;
    for (int i = t; i < 2048; i += 256) {
        int m = i >> 5;
        cq[(size_t)bh * 2048 + i] = sk[i] * invq[m];
        cv[(size_t)bh * 2048 + i] = sv[i] * invv[m];
    }
}

__global__ __launch_bounds__(256) void k_rpb(const float* __restrict__ cen,
                                             float* __restrict__ out) {
    size_t g = (size_t)blockIdx.x * 256 + threadIdx.x;   // 0 .. 16777215
    int m      = (int)(g & 63);
    size_t lbh = g >> 6;
    int l  = (int)(lbh & 4095);
    int bh = (int)(lbh >> 12);
    float fi = (float)(l >> 6);
    float fj = (float)(l & 63);
    float ch = cen[bh * NCLUS + m];
    float cw = cen[4096 + bh * NCLUS + m];
    float dh = fi - ch, dw = fj - cw;
    out[262144 + g] = expf(-sqrtf(fmaf(dh, dh, dw * dw)));
}

extern "C" void kernel_launch(void* const* d_in, const int* in_sizes, int n_in,
                              void* d_out, int out_size, void* d_ws, size_t ws_size,
                              hipStream_t stream) {
    const float* xk    = (const float*)d_in[0];
    const float* xv    = (const float*)d_in[1];
    const float* scale = (const float*)d_in[2];
    float* out = (float*)d_out;
    float* ws  = (float*)d_ws;

    float* cq0     = ws;                        // 131072 floats
    float* cen     = ws + 131072;               // 8192 floats (ch | cw)
    float* partial = ws + 139264;               // 512 * 4288 floats (~8.8 MB)
    float* rp0     = ws + 139264 + 512 * PSTRIDE; // 262144 floats (1 MB)

    k_initcenter<<<1024, 256, 0, stream>>>(xk, cq0);
    k_rpe0<<<1024, 256, 0, stream>>>(rp0);
    k_assign<<<NMAPS * CHUNKS, 512, 0, stream>>>(xk, xv, scale, cq0, rp0, partial);
    k_reduce<<<NMAPS, 256, 0, stream>>>(partial, out, cen);
    k_rpb<<<65536, 256, 0, stream>>>(cen, out);
}